// Round 1
// 854.896 us; speedup vs baseline: 1.0011x; 1.0011x over previous
//
#include <hip/hip_runtime.h>
#include <hip/hip_fp16.h>

typedef _Float16 f16x2 __attribute__((ext_vector_type(2)));
typedef _Float16 half8 __attribute__((ext_vector_type(8)));

#define TS  512
#define HID 256
#define G3  768
#define EMB 128
#define NB1 8
#define RPB 96   // rows per xi1-stage block
#define CTL 767  // poller/publisher thread
#define BSZ 8    // handshake batch (steps)

__device__ __forceinline__ float sigmoidf_(float x){ return 1.0f/(1.0f+__expf(-x)); }
__device__ __forceinline__ float tanhf_(float x){
  float e = __expf(-2.0f*fabsf(x));
  float t = (1.0f-e)/(1.0f+e);
  return copysignf(t,x);
}

// K1: xi0[t][j] = bih0[j] + sum_k Wih0[j][k] * emb[x[t,511]][k]
__global__ __launch_bounds__(256) void xi0_kernel(const int* __restrict__ x,
    const float* __restrict__ emb_tab, const float* __restrict__ Wih0,
    const float* __restrict__ bih0, float* __restrict__ xi0)
{
  __shared__ float embs[8][EMB];
  __shared__ int idx8[8];
  int tid = threadIdx.x;
  int t0  = blockIdx.x * 8;
  if (tid < 8) idx8[tid] = x[(t0 + tid)*512 + 511];
  __syncthreads();
  for (int i = tid; i < 8*EMB; i += 256){
    int q = i >> 7, r = i & 127;
    embs[q][r] = emb_tab[(long)idx8[q]*EMB + r];
  }
  __syncthreads();
  for (int g = 0; g < 3; g++){
    int j = g*256 + tid;
    float b = bih0[j];
    float acc[8];
    #pragma unroll
    for (int u=0;u<8;u++) acc[u]=b;
    const float4* wrow = (const float4*)(Wih0 + (long)j*EMB);
    #pragma unroll 8
    for (int m=0;m<EMB/4;m++){
      float4 w = wrow[m];
      #pragma unroll
      for (int u=0;u<8;u++){
        acc[u] += w.x*embs[u][4*m+0] + w.y*embs[u][4*m+1]
                + w.z*embs[u][4*m+2] + w.w*embs[u][4*m+3];
      }
    }
    #pragma unroll
    for (int u=0;u<8;u++) xi0[(long)(t0+u)*G3 + j] = acc[u];
  }
}

// ---------------- pipelined recurrence (1 kernel, 10 blocks) ----------------
// ROUND-14: round-13's amdgpu_max_num_work_groups was ignored (VGPR_Count
// still 84, step still ~3430 cy — the spill wall). Mechanism finally
// identified: the RA budget comes from SIMachineFunctionInfo's occupancy
// estimate getOccupancyWithWorkGroupSizes() — for a 768-thr / 7.7KB-LDS wg
// that's 2 wg/CU = 6 waves/EU -> budget 512/6 = 84 — clamped only by the
// *max* of amdgpu-waves-per-eu. __launch_bounds__(768,3) sets only the MIN
// (never consulted by the clamp); max_num_work_groups isn't consulted at
// all. Fix: set the MAX explicitly via amdgpu_waves_per_eu(3,3) ->
// occupancy estimate clamps to 3 waves/EU -> budget 168 regs. Demand is
// ~163 (128 weight regs + ~35 working) -> zero/near-zero spill. Occupancy
// cost: none (grid = 10 blocks on 256 CUs; 1 wg/CU is what we want, all 10
// pipeline blocks still co-resident). Tell: VGPR_Count 84 -> ~160+; pipe
// 732 -> ~230-300 us (step ~3430 -> ~1000-1300 cy).
#define SHUF(V,A,B) __builtin_shufflevector(V,V,A,B)
#define WR32(X) X(0,0) X(0,1) X(0,2) X(0,3) X(1,0) X(1,1) X(1,2) X(1,3) \
                X(2,0) X(2,1) X(2,2) X(2,3) X(3,0) X(3,1) X(3,2) X(3,3) \
                X(4,0) X(4,1) X(4,2) X(4,3) X(5,0) X(5,1) X(5,2) X(5,3) \
                X(6,0) X(6,1) X(6,2) X(6,3) X(7,0) X(7,1) X(7,2) X(7,3)

template<int MODE>  // 0 = producer (layer 1), 1 = consumer (layer 2)
__device__ __forceinline__ void rec_layer(const float* __restrict__ Whh,
    const float* __restrict__ bhh, const float* __restrict__ xi,
    _Float16* __restrict__ h16out, float* __restrict__ f32out,
    unsigned* __restrict__ flagB, unsigned* __restrict__ cntB,
    _Float16 (*hbuf)[8*40], float* gh, float* bhhL)
{
  int tid = threadIdx.x;
  int g   = tid >> 3;        // 0..95 : rows 8g..8g+7
  int o   = tid & 7;         // col chunk [32o, 32o+32)

#define WDECL(I,C) half8 w##I##_##C;
  WR32(WDECL)
#define WLOAD(I,C) { \
    const float4* p_ = (const float4*)(Whh + (long)(8*g+(I))*HID + 32*o + 8*(C)); \
    float4 u_ = p_[0], v_ = p_[1]; \
    w##I##_##C = (half8){(_Float16)u_.x,(_Float16)u_.y,(_Float16)u_.z,(_Float16)u_.w, \
                         (_Float16)v_.x,(_Float16)v_.y,(_Float16)v_.z,(_Float16)v_.w}; }
  WR32(WLOAD)

  float hprev = 0.f;
  float xr=0.f, xz=0.f, xn=0.f;
  bhhL[tid] = bhh[tid];                       // biases live in LDS (3 regs saved)
  if (tid < 80) ((half8*)hbuf)[tid] = (half8)(_Float16)0;  // zero both buffers

  if (MODE == 1 && tid == CTL){   // wait for batch 0 of xi1
    while (__hip_atomic_load(&cntB[0], __ATOMIC_RELAXED, __HIP_MEMORY_SCOPE_AGENT) < NB1)
      __builtin_amdgcn_s_sleep(1);
    __threadfence();
  }
  __syncthreads();
  if (tid < HID){  // xi for t=0 (MODE1: safe after cntB[0] confirmed)
    xr = xi[tid]; xz = xi[HID+tid]; xn = xi[2*HID+tid];
  }

  for (int t = 0; t < TS; t++){
    // consumer: at the last step of a batch, confirm the NEXT batch so the
    // elementwise-phase prefetch of xi[t+1] is safe.
    if (MODE == 1 && tid == CTL && ((t+1) & (BSZ-1)) == 0 && t+1 < TS){
      unsigned b = (unsigned)(t+1) >> 3;
      while (__hip_atomic_load(&cntB[b], __ATOMIC_RELAXED, __HIP_MEMORY_SCOPE_AGENT) < NB1)
        __builtin_amdgcn_s_sleep(1);
      __threadfence();
    }

    // ---- dot phase: 4 h-chunk reads, 128 fdot2, accs a0..a7 ----
    const half8* hp = (const half8*)(&hbuf[t & 1][o*40]);
    float a0=0.f,a1=0.f,a2=0.f,a3=0.f,a4=0.f,a5=0.f,a6=0.f,a7=0.f;
#define DOT1(I,C,HV) \
    a##I = __builtin_amdgcn_fdot2(SHUF(w##I##_##C,0,1), SHUF(HV,0,1), a##I, false); \
    a##I = __builtin_amdgcn_fdot2(SHUF(w##I##_##C,2,3), SHUF(HV,2,3), a##I, false); \
    a##I = __builtin_amdgcn_fdot2(SHUF(w##I##_##C,4,5), SHUF(HV,4,5), a##I, false); \
    a##I = __builtin_amdgcn_fdot2(SHUF(w##I##_##C,6,7), SHUF(HV,6,7), a##I, false);
#define DOTCHUNK(C) { half8 hv = hp[C]; \
    DOT1(0,C,hv) DOT1(1,C,hv) DOT1(2,C,hv) DOT1(3,C,hv) \
    DOT1(4,C,hv) DOT1(5,C,hv) DOT1(6,C,hv) DOT1(7,C,hv) }
    DOTCHUNK(0) DOTCHUNK(1) DOTCHUNK(2) DOTCHUNK(3)

    // ---- 8-lane butterfly; lane o ends with full dot of row 8g+o == tid ----
    bool b0 = o & 1, b1 = o & 2, b2 = o & 4;
    float s, r_;
    s = b0 ? a0 : a1; r_ = __shfl_xor(s, 1, 64); float c0 = (b0 ? a1 : a0) + r_;
    s = b0 ? a2 : a3; r_ = __shfl_xor(s, 1, 64); float c1 = (b0 ? a3 : a2) + r_;
    s = b0 ? a4 : a5; r_ = __shfl_xor(s, 1, 64); float c2 = (b0 ? a5 : a4) + r_;
    s = b0 ? a6 : a7; r_ = __shfl_xor(s, 1, 64); float c3 = (b0 ? a7 : a6) + r_;
    s = b1 ? c0 : c1; r_ = __shfl_xor(s, 2, 64); float d0 = (b1 ? c1 : c0) + r_;
    s = b1 ? c2 : c3; r_ = __shfl_xor(s, 2, 64); float d1 = (b1 ? c3 : c2) + r_;
    s = b2 ? d0 : d1; r_ = __shfl_xor(s, 4, 64); float e  = (b2 ? d1 : d0) + r_;
    gh[tid] = e;
    __syncthreads();

    // ---- elementwise phase: unit j = tid < 256 ----
    if (tid < HID){
      float r = sigmoidf_(xr + bhhL[tid] + gh[tid]);
      float z = sigmoidf_(xz + bhhL[HID+tid] + gh[HID+tid]);
      float n = tanhf_(xn + r*(gh[2*HID+tid] + bhhL[2*HID+tid]));
      float hnew = (1.0f - z)*n + z*hprev;
      hprev = hnew;
      if (MODE == 1) f32out[(long)t*HID + tid] = hnew;
      float partner = __shfl_xor(hnew, 1, 64);
      if ((tid & 1) == 0){
        f16x2 p; p.x = (_Float16)hnew; p.y = (_Float16)partner;
        *(f16x2*)(&hbuf[(t+1)&1][(tid>>5)*40 + (tid&31)]) = p;
        if (MODE == 0) *(f16x2*)(h16out + (long)t*HID + tid) = p;
      }
      if (t+1 < TS){  // prefetch xi[t+1]; latency rides under next dot phase
        const float* xp = xi + (long)(t+1)*G3;
        xr = xp[tid]; xz = xp[HID+tid]; xn = xp[2*HID+tid];
      }
    }
    __syncthreads();
    // producer: publish once per batch
    if (MODE == 0 && tid == CTL && ((t+1) & (BSZ-1)) == 0){
      __threadfence();
      __hip_atomic_store(&flagB[t >> 3], 1u, __ATOMIC_RELEASE, __HIP_MEMORY_SCOPE_AGENT);
    }
  }
}

__device__ __forceinline__ void xi1_stage(const float* __restrict__ Wih1,
    const float* __restrict__ bih1, const _Float16* __restrict__ h16,
    float* __restrict__ xi1, unsigned* __restrict__ flagB,
    unsigned* __restrict__ cntB, int slice)
{
  int tid = threadIdx.x;
  int r = tid >> 3, o = tid & 7;        // row r of slice; cols [32o,32o+32)
  int row = slice*RPB + r;
  half8 w0,w1,w2,w3;                    // 16 VGPRs, register-resident slice
  {
    const float4* wp = (const float4*)(Wih1 + (long)row*HID + o*32);
    float4 p0=wp[0],p1=wp[1],p2=wp[2],p3=wp[3],p4=wp[4],p5=wp[5],p6=wp[6],p7=wp[7];
    w0 = (half8){(_Float16)p0.x,(_Float16)p0.y,(_Float16)p0.z,(_Float16)p0.w,
                 (_Float16)p1.x,(_Float16)p1.y,(_Float16)p1.z,(_Float16)p1.w};
    w1 = (half8){(_Float16)p2.x,(_Float16)p2.y,(_Float16)p2.z,(_Float16)p2.w,
                 (_Float16)p3.x,(_Float16)p3.y,(_Float16)p3.z,(_Float16)p3.w};
    w2 = (half8){(_Float16)p4.x,(_Float16)p4.y,(_Float16)p4.z,(_Float16)p4.w,
                 (_Float16)p5.x,(_Float16)p5.y,(_Float16)p5.z,(_Float16)p5.w};
    w3 = (half8){(_Float16)p6.x,(_Float16)p6.y,(_Float16)p6.z,(_Float16)p6.w,
                 (_Float16)p7.x,(_Float16)p7.y,(_Float16)p7.z,(_Float16)p7.w};
  }
  float bias = bih1[row];

  for (int b = 0; b < TS/BSZ; b++){
    if (tid == 0){
      while (__hip_atomic_load(&flagB[b], __ATOMIC_RELAXED, __HIP_MEMORY_SCOPE_AGENT) == 0u)
        __builtin_amdgcn_s_sleep(1);
      __threadfence();
    }
    __syncthreads();
    #pragma unroll 4
    for (int u = 0; u < BSZ; u++){
      int t = b*BSZ + u;
      const half8* hp = (const half8*)(h16 + (long)t*HID + o*32);
      half8 h0 = hp[0], h1 = hp[1], h2 = hp[2], h3 = hp[3];
      float acc = 0.f;
#define XDOT(W,H) \
      acc = __builtin_amdgcn_fdot2(SHUF(W,0,1), SHUF(H,0,1), acc, false); \
      acc = __builtin_amdgcn_fdot2(SHUF(W,2,3), SHUF(H,2,3), acc, false); \
      acc = __builtin_amdgcn_fdot2(SHUF(W,4,5), SHUF(H,4,5), acc, false); \
      acc = __builtin_amdgcn_fdot2(SHUF(W,6,7), SHUF(H,6,7), acc, false);
      XDOT(w0,h0) XDOT(w1,h1) XDOT(w2,h2) XDOT(w3,h3)
      acc += __shfl_xor(acc, 1, 64);
      acc += __shfl_xor(acc, 2, 64);
      acc += __shfl_xor(acc, 4, 64);
      if (o == 0) xi1[(long)t*G3 + row] = acc + bias;
    }
    __syncthreads();   // drains each thread's stores (vmcnt) before fence
    if (tid == 0){
      __threadfence();
      atomicAdd(&cntB[b], 1u);
    }
  }
}

__global__
__attribute__((amdgpu_flat_work_group_size(768, 768),
               amdgpu_waves_per_eu(3, 3),
               amdgpu_max_num_work_groups(10, 1, 1)))
void pipe_kernel(
    const float* __restrict__ Whh0, const float* __restrict__ bhh0,
    const float* __restrict__ xi0,
    const float* __restrict__ Wih1, const float* __restrict__ bih1,
    const float* __restrict__ Whh1, const float* __restrict__ bhh1,
    _Float16* __restrict__ h1f16, float* __restrict__ xi1,
    float* __restrict__ h2, unsigned* __restrict__ flagB,
    unsigned* __restrict__ cntB)
{
  __shared__ __align__(16) _Float16 hbuf[2][8*40];
  __shared__ float gh[G3];
  __shared__ float bhhL[G3];
  int bid = blockIdx.x;
  if (bid == 0)
    rec_layer<0>(Whh0, bhh0, xi0, h1f16, nullptr, flagB, cntB, hbuf, gh, bhhL);
  else if (bid == 9)
    rec_layer<1>(Whh1, bhh1, xi1, nullptr, h2, flagB, cntB, hbuf, gh, bhhL);
  else
    xi1_stage(Wih1, bih1, h1f16, xi1, flagB, cntB, bid - 1);
}

// K5: logits[t][c] = b_out[c] + sum_i h2[t][i] * W_out[c][i]
__global__ __launch_bounds__(1024) void logits_kernel(const float* __restrict__ h2,
    const float* __restrict__ Wout, const float* __restrict__ bout,
    float* __restrict__ out)
{
  __shared__ __align__(16) float wsm[2*HID];
  __shared__ float bs[2];
  int tid = threadIdx.x;
  if (tid < 2*HID) wsm[tid] = Wout[tid];
  if (tid < 2)     bs[tid]  = bout[tid];
  __syncthreads();
  int t = tid >> 1, c = tid & 1;
  const float4* hr = (const float4*)(h2 + (long)t*HID);
  const float4* wr = (const float4*)(wsm + c*HID);
  float acc = bs[c];
  #pragma unroll 8
  for (int m=0;m<HID/4;m++){
    float4 h = hr[m]; float4 wv = wr[m];
    acc += h.x*wv.x + h.y*wv.y + h.z*wv.z + h.w*wv.w;
  }
  out[tid] = acc;
}

extern "C" void kernel_launch(void* const* d_in, const int* in_sizes, int n_in,
                              void* d_out, int out_size, void* d_ws, size_t ws_size,
                              hipStream_t stream)
{
  const int*   x    = (const int*)  d_in[0];
  const float* emb  = (const float*)d_in[1];
  const float* Wih0 = (const float*)d_in[2];
  const float* Whh0 = (const float*)d_in[3];
  const float* bih0 = (const float*)d_in[4];
  const float* bhh0 = (const float*)d_in[5];
  const float* Wih1 = (const float*)d_in[6];
  const float* Whh1 = (const float*)d_in[7];
  const float* bih1 = (const float*)d_in[8];
  const float* bhh1 = (const float*)d_in[9];
  const float* Wout = (const float*)d_in[10];
  const float* bout = (const float*)d_in[11];
  float* out = (float*)d_out;

  char* ws = (char*)d_ws;
  float*     xi0   = (float*)(ws);                       // 512*768 f32 = 1.5 MB
  float*     xi1   = (float*)(ws + 1572864);             // 512*768 f32 = 1.5 MB
  _Float16*  h1f16 = (_Float16*)(ws + 3145728);          // 512*256 f16 = 256 KB
  float*     h2    = (float*)(ws + 3407872);             // 512*256 f32 = 512 KB
  unsigned*  flagB = (unsigned*)(ws + 3932160);          // 64 u32
  unsigned*  cntB  = (unsigned*)(ws + 3934208);          // 64 u32

  hipMemsetAsync(ws + 3932160, 0, 4096, stream);
  xi0_kernel<<<64, 256, 0, stream>>>(x, emb, Wih0, bih0, xi0);
  pipe_kernel<<<10, 768, 0, stream>>>(Whh0, bhh0, xi0, Wih1, bih1,
                                      Whh1, bhh1, h1f16, xi1, h2, flagB, cntB);
  logits_kernel<<<1, 1024, 0, stream>>>(h2, Wout, bout, out);
}

// Round 2
// 851.608 us; speedup vs baseline: 1.0049x; 1.0039x over previous
//
#include <hip/hip_runtime.h>
#include <hip/hip_fp16.h>

typedef _Float16 f16x2 __attribute__((ext_vector_type(2)));
typedef _Float16 half8 __attribute__((ext_vector_type(8)));

#define TS  512
#define HID 256
#define G3  768
#define EMB 128
#define NB1 8
#define RPB 96   // rows per xi1-stage block
#define CTL 767  // poller/publisher thread
#define BSZ 8    // handshake batch (steps)

__device__ __forceinline__ float sigmoidf_(float x){ return 1.0f/(1.0f+__expf(-x)); }
__device__ __forceinline__ float tanhf_(float x){
  float e = __expf(-2.0f*fabsf(x));
  float t = (1.0f-e)/(1.0f+e);
  return copysignf(t,x);
}

// K1: xi0[t][j] = bih0[j] + sum_k Wih0[j][k] * emb[x[t,511]][k]
__global__ __launch_bounds__(256) void xi0_kernel(const int* __restrict__ x,
    const float* __restrict__ emb_tab, const float* __restrict__ Wih0,
    const float* __restrict__ bih0, float* __restrict__ xi0)
{
  __shared__ float embs[8][EMB];
  __shared__ int idx8[8];
  int tid = threadIdx.x;
  int t0  = blockIdx.x * 8;
  if (tid < 8) idx8[tid] = x[(t0 + tid)*512 + 511];
  __syncthreads();
  for (int i = tid; i < 8*EMB; i += 256){
    int q = i >> 7, r = i & 127;
    embs[q][r] = emb_tab[(long)idx8[q]*EMB + r];
  }
  __syncthreads();
  for (int g = 0; g < 3; g++){
    int j = g*256 + tid;
    float b = bih0[j];
    float acc[8];
    #pragma unroll
    for (int u=0;u<8;u++) acc[u]=b;
    const float4* wrow = (const float4*)(Wih0 + (long)j*EMB);
    #pragma unroll 8
    for (int m=0;m<EMB/4;m++){
      float4 w = wrow[m];
      #pragma unroll
      for (int u=0;u<8;u++){
        acc[u] += w.x*embs[u][4*m+0] + w.y*embs[u][4*m+1]
                + w.z*embs[u][4*m+2] + w.w*embs[u][4*m+3];
      }
    }
    #pragma unroll
    for (int u=0;u<8;u++) xi0[(long)(t0+u)*G3 + j] = acc[u];
  }
}

// ---------------- pipelined recurrence (1 kernel, 10 blocks) ----------------
// ROUND-15: rounds 13-14 proved the attribute path dead — both
// amdgpu_max_num_work_groups(10,1,1) and amdgpu_waves_per_eu(3,3) left
// VGPR_Count at exactly 84 (= 512/6: the RA budget for the 6-waves/EU
// occupancy estimate of a 768-thr / 7.7KB-LDS workgroup). New lever: feed
// the occupancy FORMULA an input it cannot ignore. A static LDS allocation
// of 96 KB (> 160KB/2) makes getOccupancyWithWorkGroupSizes LDS-limited:
// floor(160K/96K) = 1 wg/CU -> 12 waves/CU -> 3 waves/EU -> VGPR budget
// 512/3 ~ 168. Demand is ~158 (128 weight regs + ~30 working) -> spills
// (~200 KB/step scratch<->L2, the 3300cy wall) drop to ~zero. Runtime cost
// of the pad: none — grid is 10 blocks on 256 CUs, already 1 wg/CU; the
// extra LDS is never contended. Data (hbuf/gh/bhhL, 7.4 KB) lives inside
// the padded array so it is genuinely referenced.
// Tells: LDS_Block_Size 7680 -> ~98304; VGPR_Count 84 -> >=150;
// pipe 732 -> ~250-320 us.
#define SHUF(V,A,B) __builtin_shufflevector(V,V,A,B)
#define WR32(X) X(0,0) X(0,1) X(0,2) X(0,3) X(1,0) X(1,1) X(1,2) X(1,3) \
                X(2,0) X(2,1) X(2,2) X(2,3) X(3,0) X(3,1) X(3,2) X(3,3) \
                X(4,0) X(4,1) X(4,2) X(4,3) X(5,0) X(5,1) X(5,2) X(5,3) \
                X(6,0) X(6,1) X(6,2) X(6,3) X(7,0) X(7,1) X(7,2) X(7,3)

template<int MODE>  // 0 = producer (layer 1), 1 = consumer (layer 2)
__device__ __forceinline__ void rec_layer(const float* __restrict__ Whh,
    const float* __restrict__ bhh, const float* __restrict__ xi,
    _Float16* __restrict__ h16out, float* __restrict__ f32out,
    unsigned* __restrict__ flagB, unsigned* __restrict__ cntB,
    _Float16 (*hbuf)[8*40], float* gh, float* bhhL)
{
  int tid = threadIdx.x;
  int g   = tid >> 3;        // 0..95 : rows 8g..8g+7
  int o   = tid & 7;         // col chunk [32o, 32o+32)

#define WDECL(I,C) half8 w##I##_##C;
  WR32(WDECL)
#define WLOAD(I,C) { \
    const float4* p_ = (const float4*)(Whh + (long)(8*g+(I))*HID + 32*o + 8*(C)); \
    float4 u_ = p_[0], v_ = p_[1]; \
    w##I##_##C = (half8){(_Float16)u_.x,(_Float16)u_.y,(_Float16)u_.z,(_Float16)u_.w, \
                         (_Float16)v_.x,(_Float16)v_.y,(_Float16)v_.z,(_Float16)v_.w}; }
  WR32(WLOAD)

  float hprev = 0.f;
  float xr=0.f, xz=0.f, xn=0.f;
  bhhL[tid] = bhh[tid];                       // biases live in LDS (3 regs saved)
  if (tid < 80) ((half8*)hbuf)[tid] = (half8)(_Float16)0;  // zero both buffers

  if (MODE == 1 && tid == CTL){   // wait for batch 0 of xi1
    while (__hip_atomic_load(&cntB[0], __ATOMIC_RELAXED, __HIP_MEMORY_SCOPE_AGENT) < NB1)
      __builtin_amdgcn_s_sleep(1);
    __threadfence();
  }
  __syncthreads();
  if (tid < HID){  // xi for t=0 (MODE1: safe after cntB[0] confirmed)
    xr = xi[tid]; xz = xi[HID+tid]; xn = xi[2*HID+tid];
  }

  for (int t = 0; t < TS; t++){
    // consumer: at the last step of a batch, confirm the NEXT batch so the
    // elementwise-phase prefetch of xi[t+1] is safe.
    if (MODE == 1 && tid == CTL && ((t+1) & (BSZ-1)) == 0 && t+1 < TS){
      unsigned b = (unsigned)(t+1) >> 3;
      while (__hip_atomic_load(&cntB[b], __ATOMIC_RELAXED, __HIP_MEMORY_SCOPE_AGENT) < NB1)
        __builtin_amdgcn_s_sleep(1);
      __threadfence();
    }

    // ---- dot phase: 4 h-chunk reads, 128 fdot2, accs a0..a7 ----
    const half8* hp = (const half8*)(&hbuf[t & 1][o*40]);
    float a0=0.f,a1=0.f,a2=0.f,a3=0.f,a4=0.f,a5=0.f,a6=0.f,a7=0.f;
#define DOT1(I,C,HV) \
    a##I = __builtin_amdgcn_fdot2(SHUF(w##I##_##C,0,1), SHUF(HV,0,1), a##I, false); \
    a##I = __builtin_amdgcn_fdot2(SHUF(w##I##_##C,2,3), SHUF(HV,2,3), a##I, false); \
    a##I = __builtin_amdgcn_fdot2(SHUF(w##I##_##C,4,5), SHUF(HV,4,5), a##I, false); \
    a##I = __builtin_amdgcn_fdot2(SHUF(w##I##_##C,6,7), SHUF(HV,6,7), a##I, false);
#define DOTCHUNK(C) { half8 hv = hp[C]; \
    DOT1(0,C,hv) DOT1(1,C,hv) DOT1(2,C,hv) DOT1(3,C,hv) \
    DOT1(4,C,hv) DOT1(5,C,hv) DOT1(6,C,hv) DOT1(7,C,hv) }
    DOTCHUNK(0) DOTCHUNK(1) DOTCHUNK(2) DOTCHUNK(3)

    // ---- 8-lane butterfly; lane o ends with full dot of row 8g+o == tid ----
    bool b0 = o & 1, b1 = o & 2, b2 = o & 4;
    float s, r_;
    s = b0 ? a0 : a1; r_ = __shfl_xor(s, 1, 64); float c0 = (b0 ? a1 : a0) + r_;
    s = b0 ? a2 : a3; r_ = __shfl_xor(s, 1, 64); float c1 = (b0 ? a3 : a2) + r_;
    s = b0 ? a4 : a5; r_ = __shfl_xor(s, 1, 64); float c2 = (b0 ? a5 : a4) + r_;
    s = b0 ? a6 : a7; r_ = __shfl_xor(s, 1, 64); float c3 = (b0 ? a7 : a6) + r_;
    s = b1 ? c0 : c1; r_ = __shfl_xor(s, 2, 64); float d0 = (b1 ? c1 : c0) + r_;
    s = b1 ? c2 : c3; r_ = __shfl_xor(s, 2, 64); float d1 = (b1 ? c3 : c2) + r_;
    s = b2 ? d0 : d1; r_ = __shfl_xor(s, 4, 64); float e  = (b2 ? d1 : d0) + r_;
    gh[tid] = e;
    __syncthreads();

    // ---- elementwise phase: unit j = tid < 256 ----
    if (tid < HID){
      float r = sigmoidf_(xr + bhhL[tid] + gh[tid]);
      float z = sigmoidf_(xz + bhhL[HID+tid] + gh[HID+tid]);
      float n = tanhf_(xn + r*(gh[2*HID+tid] + bhhL[2*HID+tid]));
      float hnew = (1.0f - z)*n + z*hprev;
      hprev = hnew;
      if (MODE == 1) f32out[(long)t*HID + tid] = hnew;
      float partner = __shfl_xor(hnew, 1, 64);
      if ((tid & 1) == 0){
        f16x2 p; p.x = (_Float16)hnew; p.y = (_Float16)partner;
        *(f16x2*)(&hbuf[(t+1)&1][(tid>>5)*40 + (tid&31)]) = p;
        if (MODE == 0) *(f16x2*)(h16out + (long)t*HID + tid) = p;
      }
      if (t+1 < TS){  // prefetch xi[t+1]; latency rides under next dot phase
        const float* xp = xi + (long)(t+1)*G3;
        xr = xp[tid]; xz = xp[HID+tid]; xn = xp[2*HID+tid];
      }
    }
    __syncthreads();
    // producer: publish once per batch
    if (MODE == 0 && tid == CTL && ((t+1) & (BSZ-1)) == 0){
      __threadfence();
      __hip_atomic_store(&flagB[t >> 3], 1u, __ATOMIC_RELEASE, __HIP_MEMORY_SCOPE_AGENT);
    }
  }
}

__device__ __forceinline__ void xi1_stage(const float* __restrict__ Wih1,
    const float* __restrict__ bih1, const _Float16* __restrict__ h16,
    float* __restrict__ xi1, unsigned* __restrict__ flagB,
    unsigned* __restrict__ cntB, int slice)
{
  int tid = threadIdx.x;
  int r = tid >> 3, o = tid & 7;        // row r of slice; cols [32o,32o+32)
  int row = slice*RPB + r;
  half8 w0,w1,w2,w3;                    // 16 VGPRs, register-resident slice
  {
    const float4* wp = (const float4*)(Wih1 + (long)row*HID + o*32);
    float4 p0=wp[0],p1=wp[1],p2=wp[2],p3=wp[3],p4=wp[4],p5=wp[5],p6=wp[6],p7=wp[7];
    w0 = (half8){(_Float16)p0.x,(_Float16)p0.y,(_Float16)p0.z,(_Float16)p0.w,
                 (_Float16)p1.x,(_Float16)p1.y,(_Float16)p1.z,(_Float16)p1.w};
    w1 = (half8){(_Float16)p2.x,(_Float16)p2.y,(_Float16)p2.z,(_Float16)p2.w,
                 (_Float16)p3.x,(_Float16)p3.y,(_Float16)p3.z,(_Float16)p3.w};
    w2 = (half8){(_Float16)p4.x,(_Float16)p4.y,(_Float16)p4.z,(_Float16)p4.w,
                 (_Float16)p5.x,(_Float16)p5.y,(_Float16)p5.z,(_Float16)p5.w};
    w3 = (half8){(_Float16)p6.x,(_Float16)p6.y,(_Float16)p6.z,(_Float16)p6.w,
                 (_Float16)p7.x,(_Float16)p7.y,(_Float16)p7.z,(_Float16)p7.w};
  }
  float bias = bih1[row];

  for (int b = 0; b < TS/BSZ; b++){
    if (tid == 0){
      while (__hip_atomic_load(&flagB[b], __ATOMIC_RELAXED, __HIP_MEMORY_SCOPE_AGENT) == 0u)
        __builtin_amdgcn_s_sleep(1);
      __threadfence();
    }
    __syncthreads();
    #pragma unroll 4
    for (int u = 0; u < BSZ; u++){
      int t = b*BSZ + u;
      const half8* hp = (const half8*)(h16 + (long)t*HID + o*32);
      half8 h0 = hp[0], h1 = hp[1], h2 = hp[2], h3 = hp[3];
      float acc = 0.f;
#define XDOT(W,H) \
      acc = __builtin_amdgcn_fdot2(SHUF(W,0,1), SHUF(H,0,1), acc, false); \
      acc = __builtin_amdgcn_fdot2(SHUF(W,2,3), SHUF(H,2,3), acc, false); \
      acc = __builtin_amdgcn_fdot2(SHUF(W,4,5), SHUF(H,4,5), acc, false); \
      acc = __builtin_amdgcn_fdot2(SHUF(W,6,7), SHUF(H,6,7), acc, false);
      XDOT(w0,h0) XDOT(w1,h1) XDOT(w2,h2) XDOT(w3,h3)
      acc += __shfl_xor(acc, 1, 64);
      acc += __shfl_xor(acc, 2, 64);
      acc += __shfl_xor(acc, 4, 64);
      if (o == 0) xi1[(long)t*G3 + row] = acc + bias;
    }
    __syncthreads();   // drains each thread's stores (vmcnt) before fence
    if (tid == 0){
      __threadfence();
      atomicAdd(&cntB[b], 1u);
    }
  }
}

__global__
__attribute__((amdgpu_flat_work_group_size(768, 768),
               amdgpu_waves_per_eu(3, 3)))
void pipe_kernel(
    const float* __restrict__ Whh0, const float* __restrict__ bhh0,
    const float* __restrict__ xi0,
    const float* __restrict__ Wih1, const float* __restrict__ bih1,
    const float* __restrict__ Whh1, const float* __restrict__ bhh1,
    _Float16* __restrict__ h1f16, float* __restrict__ xi1,
    float* __restrict__ h2, unsigned* __restrict__ flagB,
    unsigned* __restrict__ cntB)
{
  // 96 KB static LDS. Real data occupies the first ~7.4 KB; the remainder
  // exists to make the backend's occupancy estimate LDS-limited (1 wg/CU ->
  // 3 waves/EU -> VGPR budget ~168 instead of 84). Runtime cost: none
  // (grid = 10 blocks on 256 CUs; never more than 1 wg/CU anyway).
  __shared__ __align__(16) float smem[24576];
  _Float16 (*hbuf)[8*40] = (_Float16 (*)[8*40])smem;   // 2*320 f16 = 1280 B
  float* gh   = smem + 512;                            // 768 f32 = 3072 B
  float* bhhL = smem + 512 + G3;                       // 768 f32 = 3072 B
  int bid = blockIdx.x;
  if (bid == 0)
    rec_layer<0>(Whh0, bhh0, xi0, h1f16, nullptr, flagB, cntB, hbuf, gh, bhhL);
  else if (bid == 9)
    rec_layer<1>(Whh1, bhh1, xi1, nullptr, h2, flagB, cntB, hbuf, gh, bhhL);
  else
    xi1_stage(Wih1, bih1, h1f16, xi1, flagB, cntB, bid - 1);
}

// K5: logits[t][c] = b_out[c] + sum_i h2[t][i] * W_out[c][i]
__global__ __launch_bounds__(1024) void logits_kernel(const float* __restrict__ h2,
    const float* __restrict__ Wout, const float* __restrict__ bout,
    float* __restrict__ out)
{
  __shared__ __align__(16) float wsm[2*HID];
  __shared__ float bs[2];
  int tid = threadIdx.x;
  if (tid < 2*HID) wsm[tid] = Wout[tid];
  if (tid < 2)     bs[tid]  = bout[tid];
  __syncthreads();
  int t = tid >> 1, c = tid & 1;
  const float4* hr = (const float4*)(h2 + (long)t*HID);
  const float4* wr = (const float4*)(wsm + c*HID);
  float acc = bs[c];
  #pragma unroll 8
  for (int m=0;m<HID/4;m++){
    float4 h = hr[m]; float4 wv = wr[m];
    acc += h.x*wv.x + h.y*wv.y + h.z*wv.z + h.w*wv.w;
  }
  out[tid] = acc;
}

extern "C" void kernel_launch(void* const* d_in, const int* in_sizes, int n_in,
                              void* d_out, int out_size, void* d_ws, size_t ws_size,
                              hipStream_t stream)
{
  const int*   x    = (const int*)  d_in[0];
  const float* emb  = (const float*)d_in[1];
  const float* Wih0 = (const float*)d_in[2];
  const float* Whh0 = (const float*)d_in[3];
  const float* bih0 = (const float*)d_in[4];
  const float* bhh0 = (const float*)d_in[5];
  const float* Wih1 = (const float*)d_in[6];
  const float* Whh1 = (const float*)d_in[7];
  const float* bih1 = (const float*)d_in[8];
  const float* bhh1 = (const float*)d_in[9];
  const float* Wout = (const float*)d_in[10];
  const float* bout = (const float*)d_in[11];
  float* out = (float*)d_out;

  char* ws = (char*)d_ws;
  float*     xi0   = (float*)(ws);                       // 512*768 f32 = 1.5 MB
  float*     xi1   = (float*)(ws + 1572864);             // 512*768 f32 = 1.5 MB
  _Float16*  h1f16 = (_Float16*)(ws + 3145728);          // 512*256 f16 = 256 KB
  float*     h2    = (float*)(ws + 3407872);             // 512*256 f32 = 512 KB
  unsigned*  flagB = (unsigned*)(ws + 3932160);          // 64 u32
  unsigned*  cntB  = (unsigned*)(ws + 3934208);          // 64 u32

  hipMemsetAsync(ws + 3932160, 0, 4096, stream);
  xi0_kernel<<<64, 256, 0, stream>>>(x, emb, Wih0, bih0, xi0);
  pipe_kernel<<<10, 768, 0, stream>>>(Whh0, bhh0, xi0, Wih1, bih1,
                                      Whh1, bhh1, h1f16, xi1, h2, flagB, cntB);
  logits_kernel<<<1, 1024, 0, stream>>>(h2, Wout, bout, out);
}